// Round 5
// baseline (666.245 us; speedup 1.0000x reference)
//
#include <hip/hip_runtime.h>

// OnceAggregation R5: R4 structure + cross-iteration gather prefetch in point_fused.
//   memset(counts) ; pack_hist (5 weight packs + out_coors + histogram) ; scan ;
//   scatter(sidx) ; point_fused (prefetched gather -> L1 -> L2 -> {x2 seq, out scatter}) ;
//   segmax (sequential stream, x4 unroll) ; vox_fused.
// Feature order of x2/agg is permuted by pi (in-register fragment chaining);
// downstream packs compensate. Swapped-operand MFMA (y^T = W^T x^T) everywhere.

typedef __attribute__((ext_vector_type(4))) float f32x4;
typedef __attribute__((ext_vector_type(8))) short s16x8;
typedef __attribute__((ext_vector_type(4))) unsigned short u16x4;
typedef __attribute__((ext_vector_type(4))) unsigned int u32x4;

static constexpr int NP = 500000;
static constexpr int NV = 60000;

__device__ __forceinline__ unsigned short f2bf(float f){
  unsigned int u = __float_as_uint(f);
  u = (u + 0x7FFFu + ((u >> 16) & 1u)) >> 16;   // RNE
  return (unsigned short)u;
}

__device__ __forceinline__ unsigned int cvtpk(float lo, float hi){
  unsigned int r;
  asm("v_cvt_pk_bf16_f32 %0, %1, %2" : "=v"(r) : "v"(lo), "v"(hi));
  return r;
}

// ---------------- pack weights + out_coors + histogram, one launch ----------------
__device__ __forceinline__ void pack_one(const float* __restrict__ w,
                                         unsigned short* __restrict__ dst,
                                         int K, int C, bool perm, int idx){
  int j = idx & 7, l = (idx >> 3) & 63, rest = idx >> 9;
  int kcn = K >> 5;
  int kc = rest % kcn, n = rest / kcn;
  int g = l >> 4, t = l & 15;
  int k = perm ? (kc * 32 + ((j >> 2) << 4) + g * 4 + (j & 3))
               : (kc * 32 + g * 8 + j);
  dst[idx] = f2bf(w[(size_t)k * C + n * 16 + t]);
}

__global__ void pack_hist_kernel(const float* __restrict__ w1, const float* __restrict__ w2,
                                 const float* __restrict__ ow, const float* __restrict__ pw1,
                                 const float* __restrict__ pw2,
                                 unsigned short* __restrict__ w1p, unsigned short* __restrict__ w2p,
                                 unsigned short* __restrict__ owp, unsigned short* __restrict__ pw1p,
                                 unsigned short* __restrict__ pw2p,
                                 float* __restrict__ out_coors,
                                 const int* __restrict__ coors, int* __restrict__ counts){
  int stride = gridDim.x * blockDim.x;
  const int T = 196608 + NV + NP;
  for (int i = blockIdx.x * blockDim.x + threadIdx.x; i < T; i += stride){
    if      (i < 16384)       pack_one(w1,  w1p,  128, 128, false, i);
    else if (i < 49152)       pack_one(w2,  w2p,  128, 256, true,  i - 16384);
    else if (i < 65536)       pack_one(ow,  owp,  256, 64,  true,  i - 49152);
    else if (i < 131072)      pack_one(pw1, pw1p, 256, 256, true,  i - 65536);
    else if (i < 196608)      pack_one(pw2, pw2p, 256, 256, true,  i - 131072);
    else if (i < 196608 + NV) out_coors[i - 196608] = (float)(i - 196608);
    else                      atomicAdd(&counts[coors[i - 196608 - NV]], 1);
  }
}

// ---------------- counting sort (scan + scatter) ----------------
__global__ __launch_bounds__(1024)
void scan_kernel(const int* __restrict__ counts, int* __restrict__ offsets,
                 int* __restrict__ cursor){
  __shared__ int part[1024];
  const int t = threadIdx.x;
  constexpr int PER = (NV + 1023) / 1024;
  int base = t * PER;
  int s = 0;
  for (int i = 0; i < PER; ++i){ int b = base + i; if (b < NV) s += counts[b]; }
  part[t] = s;
  __syncthreads();
  for (int d = 1; d < 1024; d <<= 1){
    int u = (t >= d) ? part[t - d] : 0;
    __syncthreads();
    part[t] += u;
    __syncthreads();
  }
  int run = (t > 0) ? part[t - 1] : 0;
  for (int i = 0; i < PER; ++i){
    int b = base + i;
    if (b < NV){ offsets[b] = run; cursor[b] = run; run += counts[b]; }
  }
  if (t == 1023) offsets[NV] = run;
}

__global__ void scatter_kernel(const int* __restrict__ coors, int* __restrict__ cursor,
                               int* __restrict__ sorted_idx){
  int stride = gridDim.x * blockDim.x;
  for (int i = blockIdx.x * blockDim.x + threadIdx.x; i < NP; i += stride){
    int v = coors[i];
    int p = atomicAdd(&cursor[v], 1);
    sorted_idx[p] = i;
  }
}

// sequential segment-max over sorted x2 rows (u16 max exact for relu'd bf16 >= 0)
__global__ __launch_bounds__(256)
void segmax_kernel(const unsigned short* __restrict__ x2, const int* __restrict__ offsets,
                   unsigned short* __restrict__ agg){
  int wid = blockIdx.x * 4 + (threadIdx.x >> 6);
  int lane = threadIdx.x & 63;
  if (wid >= NV) return;
  int beg = offsets[wid], end = offsets[wid + 1];
  const unsigned short* p = x2 + (size_t)beg * 256 + lane * 4;
  u16x4 M0 = {0,0,0,0}, M1 = {0,0,0,0}, M2 = {0,0,0,0}, M3 = {0,0,0,0};
  int n = end - beg, i = 0;
  for (; i + 4 <= n; i += 4){
    u16x4 a = *(const u16x4*)p;
    u16x4 b = *(const u16x4*)(p + 256);
    u16x4 c = *(const u16x4*)(p + 512);
    u16x4 d = *(const u16x4*)(p + 768);
    p += 1024;
#pragma unroll
    for (int j = 0; j < 4; ++j){
      M0[j] = max(M0[j], a[j]); M1[j] = max(M1[j], b[j]);
      M2[j] = max(M2[j], c[j]); M3[j] = max(M3[j], d[j]);
    }
  }
  for (; i < n; ++i){
    u16x4 a = *(const u16x4*)p; p += 256;
#pragma unroll
    for (int j = 0; j < 4; ++j) M0[j] = max(M0[j], a[j]);
  }
#pragma unroll
  for (int j = 0; j < 4; ++j) M0[j] = max(max(M0[j], M1[j]), max(M2[j], M3[j]));
  *(u16x4*)(agg + (size_t)wid * 256 + lane * 4) = M0;
}

// ---------------- swapped-GEMM building blocks ----------------
template<int KC, int NT>
__device__ __forceinline__ void gemm2x(const s16x8* bA, const s16x8* bB,
                                       const unsigned short* Wp,
                                       int lane, f32x4* dA, f32x4* dB){
#pragma unroll
  for (int n = 0; n < NT; ++n){
    f32x4 aA = {0.f,0.f,0.f,0.f}, aB = {0.f,0.f,0.f,0.f};
#pragma unroll
    for (int kc = 0; kc < KC; ++kc){
      s16x8 w = *(const s16x8*)(Wp + ((n * KC + kc) * 64 + lane) * 8);
      aA = __builtin_amdgcn_mfma_f32_16x16x32_bf16(w, bA[kc], aA, 0, 0, 0);
      aB = __builtin_amdgcn_mfma_f32_16x16x32_bf16(w, bB[kc], aB, 0, 0, 0);
    }
    dA[n] = aA; dB[n] = aB;
  }
}

template<int NT, int C>
__device__ __forceinline__ void bias_ln_relu_sw(f32x4* d0, f32x4* d1,
                                                const float* __restrict__ bias,
                                                const float* __restrict__ gam,
                                                const float* __restrict__ bet, int g){
  float s0 = 0.f, s1 = 0.f, q0 = 0.f, q1 = 0.f;
#pragma unroll
  for (int n = 0; n < NT; ++n){
    f32x4 bv = *(const f32x4*)(bias + n * 16 + g * 4);
#pragma unroll
    for (int i = 0; i < 4; ++i){
      float v0 = d0[n][i] + bv[i]; d0[n][i] = v0; s0 += v0; q0 += v0 * v0;
      float v1 = d1[n][i] + bv[i]; d1[n][i] = v1; s1 += v1; q1 += v1 * v1;
    }
  }
  s0 += __shfl_xor(s0, 16); s0 += __shfl_xor(s0, 32);
  q0 += __shfl_xor(q0, 16); q0 += __shfl_xor(q0, 32);
  s1 += __shfl_xor(s1, 16); s1 += __shfl_xor(s1, 32);
  q1 += __shfl_xor(q1, 16); q1 += __shfl_xor(q1, 32);
  float m0 = s0 * (1.f / C), m1 = s1 * (1.f / C);
  float r0 = rsqrtf(q0 * (1.f / C) - m0 * m0 + 1e-3f);
  float r1 = rsqrtf(q1 * (1.f / C) - m1 * m1 + 1e-3f);
#pragma unroll
  for (int n = 0; n < NT; ++n){
    f32x4 gv  = *(const f32x4*)(gam + n * 16 + g * 4);
    f32x4 bev = *(const f32x4*)(bet + n * 16 + g * 4);
#pragma unroll
    for (int i = 0; i < 4; ++i){
      d0[n][i] = fmaxf((d0[n][i] - m0) * r0 * gv[i] + bev[i], 0.f);
      d1[n][i] = fmaxf((d1[n][i] - m1) * r1 * gv[i] + bev[i], 0.f);
    }
  }
}

// next-layer B frag[kc] = bf16{d[2kc][0..3], d[2kc+1][0..3]} (pi-permuted packs)
template<int NT>
__device__ __forceinline__ void to_frags(const f32x4* d, s16x8* f){
#pragma unroll
  for (int kc = 0; kc < NT / 2; ++kc){
    u32x4 t;
    t[0] = cvtpk(d[2*kc][0],   d[2*kc][1]);
    t[1] = cvtpk(d[2*kc][2],   d[2*kc][3]);
    t[2] = cvtpk(d[2*kc+1][0], d[2*kc+1][1]);
    t[3] = cvtpk(d[2*kc+1][2], d[2*kc+1][3]);
    f[kc] = __builtin_bit_cast(s16x8, t);
  }
}

// raw gathered feature row: lane's 32 cols as 8 f32x4 (cols q*8.., q = kc*4+g)
__device__ __forceinline__ void load_raw(const float* __restrict__ feats,
                                         const float* __restrict__ fclus,
                                         int orig, int g, f32x4* r){
  const float* rp = feats + (size_t)orig * 125;
#pragma unroll
  for (int kc = 0; kc < 3; ++kc){
    int q = kc * 4 + g;
    r[2*kc]   = *(const f32x4*)(rp + q * 8);
    r[2*kc+1] = *(const f32x4*)(rp + q * 8 + 4);
  }
  if (g < 3){
    int q = 12 + g;
    r[6] = *(const f32x4*)(rp + q * 8);
    r[7] = *(const f32x4*)(rp + q * 8 + 4);
  } else {
    const float* fc = fclus + (size_t)orig * 3;
    r[6] = *(const f32x4*)(rp + 120);
    f32x4 u1;
    u1[0] = rp[124];
    u1[1] = fc[0] * 0.05f; u1[2] = fc[1] * 0.05f; u1[3] = fc[2] * 0.25f;
    r[7] = u1;
  }
}

__device__ __forceinline__ void cvt_raw(const f32x4* r, s16x8* bf){
#pragma unroll
  for (int kc = 0; kc < 4; ++kc){
    u32x4 t;
    t[0] = cvtpk(r[2*kc][0],   r[2*kc][1]);
    t[1] = cvtpk(r[2*kc][2],   r[2*kc][3]);
    t[2] = cvtpk(r[2*kc+1][0], r[2*kc+1][1]);
    t[3] = cvtpk(r[2*kc+1][2], r[2*kc+1][3]);
    bf[kc] = __builtin_bit_cast(s16x8, t);
  }
}

// ---------------- fused point pipeline (persistent, weights in LDS, prefetch) ----------------
__global__ __launch_bounds__(512, 2)
void point_fused_kernel(const float* __restrict__ feats, const float* __restrict__ fclus,
                        const int* __restrict__ sidx,
                        const unsigned short* __restrict__ w1p,
                        const unsigned short* __restrict__ w2p,
                        const unsigned short* __restrict__ owp,
                        const float* __restrict__ b1, const float* __restrict__ g1,
                        const float* __restrict__ be1,
                        const float* __restrict__ b2, const float* __restrict__ g2,
                        const float* __restrict__ be2,
                        const float* __restrict__ ob, const float* __restrict__ og,
                        const float* __restrict__ obe,
                        unsigned short* __restrict__ x2,
                        float* __restrict__ out_pts){
  __shared__ __align__(16) unsigned short wlds[57344];   // 112 KB
  {
    s16x8* dd = (s16x8*)wlds;
    const int tt = threadIdx.x;
    for (int i = tt; i < 2048; i += 512) dd[i]        = ((const s16x8*)w1p)[i];
    for (int i = tt; i < 4096; i += 512) dd[2048 + i] = ((const s16x8*)w2p)[i];
    for (int i = tt; i < 1024; i += 512) dd[6144 + i] = ((const s16x8*)owp)[i];
  }
  __syncthreads();
  const unsigned short* wl1 = wlds;
  const unsigned short* wl2 = wlds + 16384;
  const unsigned short* wlo = wlds + 49152;

  const int lane = threadIdx.x & 63;
  const int wave = threadIdx.x >> 6;
  const int g = lane >> 4, t = lane & 15;
  const int ntiles = (NP + 255) / 256;

  int tile = blockIdx.x;
  if (tile >= ntiles) return;

  // prologue gather for first tile
  int m0 = tile * 256 + wave * 32;
  int slotA = m0 + t, slotB = m0 + 16 + t;
  int origA = sidx[min(slotA, NP - 1)];
  int origB = sidx[min(slotB, NP - 1)];
  f32x4 rawA[8], rawB[8];
  load_raw(feats, fclus, origA, g, rawA);
  load_raw(feats, fclus, origB, g, rawB);

  while (true){
    const bool okA = slotA < NP, okB = slotB < NP;

    // consume raw -> frags, freeing raw regs for the prefetch below
    s16x8 bfA[4], bfB[4];
    cvt_raw(rawA, bfA);
    cvt_raw(rawB, bfB);

    // prefetch next tile's gather into the (now dead) raw regs — hides ~1.1K cyc
    const int ntile = tile + gridDim.x;
    const bool more = ntile < ntiles;
    int nslotA = slotA, nslotB = slotB, nOrigA = origA, nOrigB = origB;
    if (more){
      int nm0 = ntile * 256 + wave * 32;
      nslotA = nm0 + t; nslotB = nm0 + 16 + t;
      nOrigA = sidx[min(nslotA, NP - 1)];
      nOrigB = sidx[min(nslotB, NP - 1)];
      load_raw(feats, fclus, nOrigA, g, rawA);
      load_raw(feats, fclus, nOrigB, g, rawB);
    }

    // layer1
    f32x4 d1a[8], d1b[8];
    gemm2x<4, 8>(bfA, bfB, wl1, lane, d1a, d1b);
    bias_ln_relu_sw<8, 128>(d1a, d1b, b1, g1, be1, g);
    s16x8 f2a[4], f2b[4];
    to_frags<8>(d1a, f2a); to_frags<8>(d1b, f2b);

    // layer2
    f32x4 d2a[16], d2b[16];
    gemm2x<4, 16>(f2a, f2b, wl2, lane, d2a, d2b);
    bias_ln_relu_sw<16, 256>(d2a, d2b, b2, g2, be2, g);
    s16x8 f3a[8], f3b[8];
    to_frags<16>(d2a, f3a); to_frags<16>(d2b, f3b);

    // x2 stores (sorted-slot order, permuted feature layout)
#pragma unroll
    for (int kc = 0; kc < 8; ++kc){
      if (okA) *(s16x8*)(x2 + (size_t)slotA * 256 + kc * 32 + g * 8) = f3a[kc];
      if (okB) *(s16x8*)(x2 + (size_t)slotB * 256 + kc * 32 + g * 8) = f3b[kc];
    }

    // out layer (scatter to original point order)
    f32x4 d3a[4], d3b[4];
    gemm2x<8, 4>(f3a, f3b, wlo, lane, d3a, d3b);
    bias_ln_relu_sw<4, 64>(d3a, d3b, ob, og, obe, g);
#pragma unroll
    for (int n = 0; n < 4; ++n){
      if (okA) *(f32x4*)(out_pts + (size_t)origA * 64 + n * 16 + g * 4) = d3a[n];
      if (okB) *(f32x4*)(out_pts + (size_t)origB * 64 + n * 16 + g * 4) = d3b[n];
    }

    if (!more) break;
    tile = ntile;
    slotA = nslotA; slotB = nslotB; origA = nOrigA; origB = nOrigB;
  }
}

// ---------------- fused voxel pipeline ----------------
__global__ __launch_bounds__(256, 2)
void vox_fused_kernel(const unsigned short* __restrict__ agg,
                      const unsigned short* __restrict__ pw1p,
                      const unsigned short* __restrict__ pw2p,
                      const float* __restrict__ pb1, const float* __restrict__ pg1,
                      const float* __restrict__ pbe1,
                      const float* __restrict__ pb2, const float* __restrict__ pg2,
                      const float* __restrict__ pbe2,
                      float* __restrict__ out_vox){
  const int lane = threadIdx.x & 63;
  const int wave = threadIdx.x >> 6;
  const int m0 = blockIdx.x * 128 + wave * 32;
  if (m0 >= NV) return;
  const int g = lane >> 4, t = lane & 15;
  const size_t mA = m0 + t, mB = m0 + 16 + t;

  s16x8 bfA[8], bfB[8];
#pragma unroll
  for (int kc = 0; kc < 8; ++kc){
    bfA[kc] = *(const s16x8*)(agg + mA * 256 + kc * 32 + g * 8);
    bfB[kc] = *(const s16x8*)(agg + mB * 256 + kc * 32 + g * 8);
  }
  f32x4 da[16], db[16];
  gemm2x<8, 16>(bfA, bfB, pw1p, lane, da, db);
  bias_ln_relu_sw<16, 256>(da, db, pb1, pg1, pbe1, g);

  s16x8 fa[8], fb[8];
  to_frags<16>(da, fa); to_frags<16>(db, fb);

  gemm2x<8, 16>(fa, fb, pw2p, lane, da, db);
  bias_ln_relu_sw<16, 256>(da, db, pb2, pg2, pbe2, g);
#pragma unroll
  for (int n = 0; n < 16; ++n){
    *(f32x4*)(out_vox + mA * 256 + n * 16 + g * 4) = da[n];
    *(f32x4*)(out_vox + mB * 256 + n * 16 + g * 4) = db[n];
  }
}

extern "C" void kernel_launch(void* const* d_in, const int* in_sizes, int n_in,
                              void* d_out, int out_size, void* d_ws, size_t ws_size,
                              hipStream_t stream){
  const float* features  = (const float*)d_in[1];
  const int*   coors     = (const int*)  d_in[2];
  const float* f_cluster = (const float*)d_in[3];
  const float* w1  = (const float*)d_in[4];
  const float* b1  = (const float*)d_in[5];
  const float* g1  = (const float*)d_in[6];
  const float* be1 = (const float*)d_in[7];
  const float* w2  = (const float*)d_in[8];
  const float* b2  = (const float*)d_in[9];
  const float* g2  = (const float*)d_in[10];
  const float* be2 = (const float*)d_in[11];
  const float* pw1 = (const float*)d_in[12];
  const float* pb1 = (const float*)d_in[13];
  const float* pg1 = (const float*)d_in[14];
  const float* pbe1= (const float*)d_in[15];
  const float* pw2 = (const float*)d_in[16];
  const float* pb2 = (const float*)d_in[17];
  const float* pg2 = (const float*)d_in[18];
  const float* pbe2= (const float*)d_in[19];
  const float* ow  = (const float*)d_in[20];
  const float* ob  = (const float*)d_in[21];
  const float* og  = (const float*)d_in[22];
  const float* obe = (const float*)d_in[23];

  char* ws = (char*)d_ws;
  unsigned short* x2   = (unsigned short*)(ws + 0);              // 256,000,000 B
  unsigned short* aggb = (unsigned short*)(ws + 256000000ull);   // 30,720,000 B
  int* counts   = (int*)(ws + 287000000ull);
  int* offsets  = (int*)(ws + 287250000ull);
  int* cursor   = (int*)(ws + 287500000ull);
  int* sidx     = (int*)(ws + 287750000ull);                     // 2,000,000 B
  unsigned short* w1p = (unsigned short*)(ws + 290000000ull);
  unsigned short* w2p = (unsigned short*)(ws + 290000000ull + 1*262144ull);
  unsigned short* owp = (unsigned short*)(ws + 290000000ull + 2*262144ull);
  unsigned short* pw1p= (unsigned short*)(ws + 290000000ull + 3*262144ull);
  unsigned short* pw2p= (unsigned short*)(ws + 290000000ull + 4*262144ull);

  float* outp      = (float*)d_out;
  float* out_pts   = outp;                       // [N,64]
  float* out_vox   = outp + 32000000;            // [V,256]
  float* out_coors = outp + 47360000;            // [V] as float

  hipMemsetAsync(counts, 0, (size_t)NV * sizeof(int), stream);

  pack_hist_kernel<<<2048, 256, 0, stream>>>(w1, w2, ow, pw1, pw2,
                                             w1p, w2p, owp, pw1p, pw2p,
                                             out_coors, coors, counts);

  scan_kernel<<<1, 1024, 0, stream>>>(counts, offsets, cursor);
  scatter_kernel<<<2048, 256, 0, stream>>>(coors, cursor, sidx);

  point_fused_kernel<<<512, 512, 0, stream>>>(
      features, f_cluster, sidx, w1p, w2p, owp,
      b1, g1, be1, b2, g2, be2, ob, og, obe, x2, out_pts);

  segmax_kernel<<<NV / 4, 256, 0, stream>>>(x2, offsets, aggb);

  vox_fused_kernel<<<(NV + 127) / 128, 256, 0, stream>>>(
      aggb, pw1p, pw2p, pb1, pg1, pbe1, pb2, pg2, pbe2, out_vox);
}

// Round 6
// 628.551 us; speedup vs baseline: 1.0600x; 1.0600x over previous
//
#include <hip/hip_runtime.h>

// OnceAggregation R6: fuse segment-max INTO point_fused via LDS tile + sorted runs.
//   memset(counts, agg) ; pack_hist ; scan(coalesced->cursor) ; scatter(sidx,vsort) ;
//   point_fused (gather -> L1 -> L2 -> {LDS tile -> run-walk segmax -> agg f32,
//                out layer -> out_pts}) ; vox_fused (agg f32 -> pl1 -> pl2).
// x2 never touches HBM (saves 512 MB). Feature order permuted by pi; packs compensate.
// Straddling voxel runs use atomicMax on f32 bits (values >= 0, idempotent).

typedef __attribute__((ext_vector_type(4))) float f32x4;
typedef __attribute__((ext_vector_type(8))) short s16x8;
typedef __attribute__((ext_vector_type(4))) unsigned int u32x4;

static constexpr int NP = 500000;
static constexpr int NV = 60000;

__device__ __forceinline__ unsigned short f2bf(float f){
  unsigned int u = __float_as_uint(f);
  u = (u + 0x7FFFu + ((u >> 16) & 1u)) >> 16;   // RNE
  return (unsigned short)u;
}

__device__ __forceinline__ unsigned int cvtpk(float lo, float hi){
  unsigned int r;
  asm("v_cvt_pk_bf16_f32 %0, %1, %2" : "=v"(r) : "v"(lo), "v"(hi));
  return r;
}

// ---------------- pack weights + out_coors + histogram ----------------
__device__ __forceinline__ void pack_one(const float* __restrict__ w,
                                         unsigned short* __restrict__ dst,
                                         int K, int C, bool perm, int idx){
  int j = idx & 7, l = (idx >> 3) & 63, rest = idx >> 9;
  int kcn = K >> 5;
  int kc = rest % kcn, n = rest / kcn;
  int g = l >> 4, t = l & 15;
  int k = perm ? (kc * 32 + ((j >> 2) << 4) + g * 4 + (j & 3))
               : (kc * 32 + g * 8 + j);
  dst[idx] = f2bf(w[(size_t)k * C + n * 16 + t]);
}

__global__ void pack_hist_kernel(const float* __restrict__ w1, const float* __restrict__ w2,
                                 const float* __restrict__ ow, const float* __restrict__ pw1,
                                 const float* __restrict__ pw2,
                                 unsigned short* __restrict__ w1p, unsigned short* __restrict__ w2p,
                                 unsigned short* __restrict__ owp, unsigned short* __restrict__ pw1p,
                                 unsigned short* __restrict__ pw2p,
                                 float* __restrict__ out_coors,
                                 const int* __restrict__ coors, int* __restrict__ counts){
  int stride = gridDim.x * blockDim.x;
  const int T = 196608 + NV + NP;
  for (int i = blockIdx.x * blockDim.x + threadIdx.x; i < T; i += stride){
    if      (i < 16384)       pack_one(w1,  w1p,  128, 128, false, i);
    else if (i < 49152)       pack_one(w2,  w2p,  128, 256, true,  i - 16384);
    else if (i < 65536)       pack_one(ow,  owp,  256, 64,  true,  i - 49152);
    else if (i < 131072)      pack_one(pw1, pw1p, 256, 256, true,  i - 65536);
    else if (i < 196608)      pack_one(pw2, pw2p, 256, 256, true,  i - 131072);
    else if (i < 196608 + NV) out_coors[i - 196608] = (float)(i - 196608);
    else                      atomicAdd(&counts[coors[i - 196608 - NV]], 1);
  }
}

// ---------------- counting sort: coalesced scan (arbitrary position order) ----------------
__global__ __launch_bounds__(1024)
void scan_kernel(const int* __restrict__ counts, int* __restrict__ cursor){
  __shared__ int part[1024];
  const int t = threadIdx.x;
  constexpr int PER = (NV + 1023) / 1024;   // 59
  int s = 0;
  for (int i = 0; i < PER; ++i){ int v = i * 1024 + t; if (v < NV) s += counts[v]; }
  part[t] = s;
  __syncthreads();
  for (int d = 1; d < 1024; d <<= 1){
    int u = (t >= d) ? part[t - d] : 0;
    __syncthreads();
    part[t] += u;
    __syncthreads();
  }
  int run = (t > 0) ? part[t - 1] : 0;
  for (int i = 0; i < PER; ++i){
    int v = i * 1024 + t;
    if (v < NV){ cursor[v] = run; run += counts[v]; }
  }
}

__global__ void scatter_kernel(const int* __restrict__ coors, int* __restrict__ cursor,
                               int* __restrict__ sidx, int* __restrict__ vsort){
  int stride = gridDim.x * blockDim.x;
  for (int i = blockIdx.x * blockDim.x + threadIdx.x; i < NP; i += stride){
    int v = coors[i];
    int p = atomicAdd(&cursor[v], 1);
    sidx[p] = i;
    vsort[p] = v;
  }
}

// ---------------- swapped-GEMM building blocks ----------------
template<int KC, int NT>
__device__ __forceinline__ void gemm2x(const s16x8* bA, const s16x8* bB,
                                       const unsigned short* __restrict__ Wp,
                                       int lane, f32x4* dA, f32x4* dB){
#pragma unroll
  for (int n = 0; n < NT; ++n){
    f32x4 aA = {0.f,0.f,0.f,0.f}, aB = {0.f,0.f,0.f,0.f};
#pragma unroll
    for (int kc = 0; kc < KC; ++kc){
      s16x8 w = *(const s16x8*)(Wp + ((n * KC + kc) * 64 + lane) * 8);
      aA = __builtin_amdgcn_mfma_f32_16x16x32_bf16(w, bA[kc], aA, 0, 0, 0);
      aB = __builtin_amdgcn_mfma_f32_16x16x32_bf16(w, bB[kc], aB, 0, 0, 0);
    }
    dA[n] = aA; dB[n] = aB;
  }
}

template<int NT, int C>
__device__ __forceinline__ void bias_ln_relu_sw(f32x4* d0, f32x4* d1,
                                                const float* __restrict__ bias,
                                                const float* __restrict__ gam,
                                                const float* __restrict__ bet, int g){
  float s0 = 0.f, s1 = 0.f, q0 = 0.f, q1 = 0.f;
#pragma unroll
  for (int n = 0; n < NT; ++n){
    f32x4 bv = *(const f32x4*)(bias + n * 16 + g * 4);
#pragma unroll
    for (int i = 0; i < 4; ++i){
      float v0 = d0[n][i] + bv[i]; d0[n][i] = v0; s0 += v0; q0 += v0 * v0;
      float v1 = d1[n][i] + bv[i]; d1[n][i] = v1; s1 += v1; q1 += v1 * v1;
    }
  }
  s0 += __shfl_xor(s0, 16); s0 += __shfl_xor(s0, 32);
  q0 += __shfl_xor(q0, 16); q0 += __shfl_xor(q0, 32);
  s1 += __shfl_xor(s1, 16); s1 += __shfl_xor(s1, 32);
  q1 += __shfl_xor(q1, 16); q1 += __shfl_xor(q1, 32);
  float m0 = s0 * (1.f / C), m1 = s1 * (1.f / C);
  float r0 = rsqrtf(q0 * (1.f / C) - m0 * m0 + 1e-3f);
  float r1 = rsqrtf(q1 * (1.f / C) - m1 * m1 + 1e-3f);
#pragma unroll
  for (int n = 0; n < NT; ++n){
    f32x4 gv  = *(const f32x4*)(gam + n * 16 + g * 4);
    f32x4 bev = *(const f32x4*)(bet + n * 16 + g * 4);
#pragma unroll
    for (int i = 0; i < 4; ++i){
      d0[n][i] = fmaxf((d0[n][i] - m0) * r0 * gv[i] + bev[i], 0.f);
      d1[n][i] = fmaxf((d1[n][i] - m1) * r1 * gv[i] + bev[i], 0.f);
    }
  }
}

template<int NT>
__device__ __forceinline__ void to_frags(const f32x4* d, s16x8* f){
#pragma unroll
  for (int kc = 0; kc < NT / 2; ++kc){
    u32x4 t;
    t[0] = cvtpk(d[2*kc][0],   d[2*kc][1]);
    t[1] = cvtpk(d[2*kc][2],   d[2*kc][3]);
    t[2] = cvtpk(d[2*kc+1][0], d[2*kc+1][1]);
    t[3] = cvtpk(d[2*kc+1][2], d[2*kc+1][3]);
    f[kc] = __builtin_bit_cast(s16x8, t);
  }
}

// gathered x-row fragments: lane (g) holds cols q*8..q*8+7, q = kc*4+g
__device__ __forceinline__ void load_x(const float* __restrict__ feats,
                                       const float* __restrict__ fclus,
                                       int orig, int g, s16x8* bf){
  const float* rp = feats + (size_t)orig * 125;
#pragma unroll
  for (int kc = 0; kc < 4; ++kc){
    f32x4 u0, u1;
    if (kc < 3 || g < 3){
      int q = kc * 4 + g;
      u0 = *(const f32x4*)(rp + q * 8);
      u1 = *(const f32x4*)(rp + q * 8 + 4);
    } else {
      const float* fc = fclus + (size_t)orig * 3;
      u0 = *(const f32x4*)(rp + 120);
      u1[0] = rp[124];
      u1[1] = fc[0] * 0.05f; u1[2] = fc[1] * 0.05f; u1[3] = fc[2] * 0.25f;
    }
    u32x4 t;
    t[0] = cvtpk(u0[0], u0[1]); t[1] = cvtpk(u0[2], u0[3]);
    t[2] = cvtpk(u1[0], u1[1]); t[3] = cvtpk(u1[2], u1[3]);
    bf[kc] = __builtin_bit_cast(s16x8, t);
  }
}

// run flush: interior -> plain store; straddles block edge -> atomicMax on f32 bits
__device__ __forceinline__ void flush_run(int v, int rs, int re, float m, int S,
                                          const int* __restrict__ vsort,
                                          float* __restrict__ agg, int c){
  if (v < 0) return;
  bool left  = (rs == 0)   && (S > 0)        && (vsort[S - 1] == v);
  bool right = (re == 128) && (S + 128 < NP) && (vsort[S + 128] == v);
  float* p = agg + (size_t)v * 256 + c;
  if (left | right) atomicMax((unsigned int*)p, __float_as_uint(m));
  else              *p = m;
}

// ---------------- fused point pipeline + in-block segment-max ----------------
__global__ __launch_bounds__(256, 2)
void point_fused_kernel(const float* __restrict__ feats, const float* __restrict__ fclus,
                        const int* __restrict__ sidx, const int* __restrict__ vsort,
                        const unsigned short* __restrict__ w1p,
                        const unsigned short* __restrict__ w2p,
                        const unsigned short* __restrict__ owp,
                        const float* __restrict__ b1, const float* __restrict__ g1,
                        const float* __restrict__ be1,
                        const float* __restrict__ b2, const float* __restrict__ g2,
                        const float* __restrict__ be2,
                        const float* __restrict__ ob, const float* __restrict__ og,
                        const float* __restrict__ obe,
                        float* __restrict__ agg,
                        float* __restrict__ out_pts){
  __shared__ __align__(16) unsigned short tile[128 * 256];   // 64 KB, swizzled slots
  const int lane = threadIdx.x & 63;
  const int wave = threadIdx.x >> 6;
  const int g = lane >> 4, t = lane & 15;
  const int S = blockIdx.x * 128;
  const int m0 = S + wave * 32;
  const int slotA = m0 + t, slotB = m0 + 16 + t;
  const bool okA = slotA < NP, okB = slotB < NP;
  const int origA = sidx[min(slotA, NP - 1)];
  const int origB = sidx[min(slotB, NP - 1)];

  // ---- GEMM pipeline (skippable for fully-OOB waves; all threads reach barrier) ----
  if (m0 < NP){
    s16x8 bfA[4], bfB[4];
    load_x(feats, fclus, origA, g, bfA);
    load_x(feats, fclus, origB, g, bfB);

    f32x4 d1a[8], d1b[8];
    gemm2x<4, 8>(bfA, bfB, w1p, lane, d1a, d1b);
    bias_ln_relu_sw<8, 128>(d1a, d1b, b1, g1, be1, g);
    s16x8 f2a[4], f2b[4];
    to_frags<8>(d1a, f2a); to_frags<8>(d1b, f2b);

    f32x4 d2a[16], d2b[16];
    gemm2x<4, 16>(f2a, f2b, w2p, lane, d2a, d2b);
    bias_ln_relu_sw<16, 256>(d2a, d2b, b2, g2, be2, g);
    s16x8 f3a[8], f3b[8];
    to_frags<16>(d2a, f3a); to_frags<16>(d2b, f3b);

    // y2 tile -> LDS (slot-swizzled: slot' = (slot&~7)|((slot&7)^(row&7)))
    const int rA = wave * 32 + t, rB = rA + 16;
#pragma unroll
    for (int kc = 0; kc < 8; ++kc){
      int s = kc * 4 + g;
      int spA = (s & ~7) | ((s & 7) ^ (rA & 7));
      int spB = (s & ~7) | ((s & 7) ^ (rB & 7));
      *(s16x8*)&tile[rA * 256 + spA * 8] = f3a[kc];
      *(s16x8*)&tile[rB * 256 + spB * 8] = f3b[kc];
    }

    // out layer (independent of segmax) -> scatter to original point order
    f32x4 d3a[4], d3b[4];
    gemm2x<8, 4>(f3a, f3b, owp, lane, d3a, d3b);
    bias_ln_relu_sw<4, 64>(d3a, d3b, ob, og, obe, g);
#pragma unroll
    for (int n = 0; n < 4; ++n){
      if (okA) *(f32x4*)(out_pts + (size_t)origA * 64 + n * 16 + g * 4) = d3a[n];
      if (okB) *(f32x4*)(out_pts + (size_t)origB * 64 + n * 16 + g * 4) = d3b[n];
    }
  }

  __syncthreads();

  // ---- phase 3: block-level segment-max over the LDS tile (thread = channel) ----
  const int c = threadIdx.x;         // 0..255
  const int slot = c >> 3, cj = c & 7;
  float m = 0.f;
  int v_prev = (S < NP) ? vsort[S] : -1;
  int rs = 0;
  for (int r = 0; r < 128; ++r){
    int v = (S + r < NP) ? vsort[S + r] : -1;
    if (r > 0 && v != v_prev){
      flush_run(v_prev, rs, r, m, S, vsort, agg, c);
      m = 0.f; rs = r; v_prev = v;
    }
    int sp = (slot & ~7) | ((slot & 7) ^ (r & 7));
    unsigned short u = tile[r * 256 + sp * 8 + cj];
    m = fmaxf(m, __uint_as_float((unsigned int)u << 16));
  }
  flush_run(v_prev, rs, 128, m, S, vsort, agg, c);
}

// ---------------- fused voxel pipeline (agg f32 -> pl1 -> pl2) ----------------
__global__ __launch_bounds__(256, 2)
void vox_fused_kernel(const float* __restrict__ agg,
                      const unsigned short* __restrict__ pw1p,
                      const unsigned short* __restrict__ pw2p,
                      const float* __restrict__ pb1, const float* __restrict__ pg1,
                      const float* __restrict__ pbe1,
                      const float* __restrict__ pb2, const float* __restrict__ pg2,
                      const float* __restrict__ pbe2,
                      float* __restrict__ out_vox){
  const int lane = threadIdx.x & 63;
  const int wave = threadIdx.x >> 6;
  const int m0 = blockIdx.x * 128 + wave * 32;
  if (m0 >= NV) return;
  const int g = lane >> 4, t = lane & 15;
  const size_t mA = m0 + t, mB = m0 + 16 + t;

  s16x8 bfA[8], bfB[8];
#pragma unroll
  for (int kc = 0; kc < 8; ++kc){
    const float* pa = agg + mA * 256 + kc * 32 + g * 8;
    const float* pb = agg + mB * 256 + kc * 32 + g * 8;
    f32x4 a0 = *(const f32x4*)pa, a1 = *(const f32x4*)(pa + 4);
    f32x4 b0 = *(const f32x4*)pb, b1v = *(const f32x4*)(pb + 4);
    u32x4 ta, tb;
    ta[0] = cvtpk(a0[0], a0[1]); ta[1] = cvtpk(a0[2], a0[3]);
    ta[2] = cvtpk(a1[0], a1[1]); ta[3] = cvtpk(a1[2], a1[3]);
    tb[0] = cvtpk(b0[0], b0[1]); tb[1] = cvtpk(b0[2], b0[3]);
    tb[2] = cvtpk(b1v[0], b1v[1]); tb[3] = cvtpk(b1v[2], b1v[3]);
    bfA[kc] = __builtin_bit_cast(s16x8, ta);
    bfB[kc] = __builtin_bit_cast(s16x8, tb);
  }
  f32x4 da[16], db[16];
  gemm2x<8, 16>(bfA, bfB, pw1p, lane, da, db);
  bias_ln_relu_sw<16, 256>(da, db, pb1, pg1, pbe1, g);

  s16x8 fa[8], fb[8];
  to_frags<16>(da, fa); to_frags<16>(db, fb);

  gemm2x<8, 16>(fa, fb, pw2p, lane, da, db);
  bias_ln_relu_sw<16, 256>(da, db, pb2, pg2, pbe2, g);
#pragma unroll
  for (int n = 0; n < 16; ++n){
    *(f32x4*)(out_vox + mA * 256 + n * 16 + g * 4) = da[n];
    *(f32x4*)(out_vox + mB * 256 + n * 16 + g * 4) = db[n];
  }
}

extern "C" void kernel_launch(void* const* d_in, const int* in_sizes, int n_in,
                              void* d_out, int out_size, void* d_ws, size_t ws_size,
                              hipStream_t stream){
  const float* features  = (const float*)d_in[1];
  const int*   coors     = (const int*)  d_in[2];
  const float* f_cluster = (const float*)d_in[3];
  const float* w1  = (const float*)d_in[4];
  const float* b1  = (const float*)d_in[5];
  const float* g1  = (const float*)d_in[6];
  const float* be1 = (const float*)d_in[7];
  const float* w2  = (const float*)d_in[8];
  const float* b2  = (const float*)d_in[9];
  const float* g2  = (const float*)d_in[10];
  const float* be2 = (const float*)d_in[11];
  const float* pw1 = (const float*)d_in[12];
  const float* pb1 = (const float*)d_in[13];
  const float* pg1 = (const float*)d_in[14];
  const float* pbe1= (const float*)d_in[15];
  const float* pw2 = (const float*)d_in[16];
  const float* pb2 = (const float*)d_in[17];
  const float* pg2 = (const float*)d_in[18];
  const float* pbe2= (const float*)d_in[19];
  const float* ow  = (const float*)d_in[20];
  const float* ob  = (const float*)d_in[21];
  const float* og  = (const float*)d_in[22];
  const float* obe = (const float*)d_in[23];

  char* ws = (char*)d_ws;
  float* aggf   = (float*)(ws + 0);                          // 61,440,000 B
  int* counts   = (int*)(ws + 61500000ull);
  int* cursor   = (int*)(ws + 61800000ull);
  int* sidx     = (int*)(ws + 62100000ull);                  // 2,000,000 B
  int* vsort    = (int*)(ws + 64200000ull);                  // 2,000,000 B
  unsigned short* w1p = (unsigned short*)(ws + 66300000ull);
  unsigned short* w2p = (unsigned short*)(ws + 66300000ull + 1*262144ull);
  unsigned short* owp = (unsigned short*)(ws + 66300000ull + 2*262144ull);
  unsigned short* pw1p= (unsigned short*)(ws + 66300000ull + 3*262144ull);
  unsigned short* pw2p= (unsigned short*)(ws + 66300000ull + 4*262144ull);

  float* outp      = (float*)d_out;
  float* out_pts   = outp;                       // [N,64]
  float* out_vox   = outp + 32000000;            // [V,256]
  float* out_coors = outp + 47360000;            // [V] as float

  hipMemsetAsync(counts, 0, (size_t)NV * sizeof(int), stream);
  hipMemsetAsync(aggf,   0, (size_t)NV * 256 * sizeof(float), stream);

  pack_hist_kernel<<<2048, 256, 0, stream>>>(w1, w2, ow, pw1, pw2,
                                             w1p, w2p, owp, pw1p, pw2p,
                                             out_coors, coors, counts);

  scan_kernel<<<1, 1024, 0, stream>>>(counts, cursor);
  scatter_kernel<<<2048, 256, 0, stream>>>(coors, cursor, sidx, vsort);

  point_fused_kernel<<<(NP + 127) / 128, 256, 0, stream>>>(
      features, f_cluster, sidx, vsort, w1p, w2p, owp,
      b1, g1, be1, b2, g2, be2, ob, og, obe, aggf, out_pts);

  vox_fused_kernel<<<(NV + 127) / 128, 256, 0, stream>>>(
      aggf, pw1p, pw2p, pb1, pg1, pbe1, pb2, pg2, pbe2, out_vox);
}